// Round 13
// baseline (565.578 us; speedup 1.0000x reference)
//
#include <hip/hip_runtime.h>
#include <math.h>

#define N_NODES 16384
#define N_EDGES 262144
#define HDIM    128
#define NG50    50
#define NLAYER  6
#define NGRAPH  16
#define TROWS   1025
#define RMAXF   4.34f

__device__ __forceinline__ float ssp_f(float x){
  return (x > 20.0f ? x : log1pf(__expf(x))) - 0.6931471805599453f;
}
__device__ __forceinline__ void fma4(float4& c, float a, const float4 b){
  c.x = fmaf(a,b.x,c.x); c.y = fmaf(a,b.y,c.y); c.z = fmaf(a,b.z,c.z); c.w = fmaf(a,b.w,c.w);
}
// bf16 helpers (RNE)
__device__ __forceinline__ unsigned short f2bf(float x){
  unsigned u = __float_as_uint(x);
  u += 0x7FFF + ((u>>16)&1);
  return (unsigned short)(u>>16);
}
__device__ __forceinline__ float bf2f(unsigned short u){
  return __uint_as_float(((unsigned)u)<<16);
}
// cooperative 32x128 fp32 chunk load, immediate global->LDS. HARD RULES:
// (R8+R10) float4s live across __syncthreads() demote to scratch. No reg prefetch.
// (R12) FR=32 tile (2 blocks/CU) loses more to occupancy than it gains in
// ds_read ratio. FR=16 is at ~90% of the LDS-read-throughput wall (R11 model).
__device__ __forceinline__ void load_chunk(float* Bs, const float* W, int kc, int tid){
  const float4* src = (const float4*)(W + kc*HDIM);
  float4* dst = (float4*)Bs;
  #pragma unroll
  for (int i=0;i<4;++i) dst[tid + i*256] = src[tid + i*256];
}

// ---------------- h = emb[z] ----------------
__global__ __launch_bounds__(256) void k_init_h(const int* __restrict__ z,
    const float* __restrict__ emb, float* __restrict__ h){
  int t = blockIdx.x*256 + threadIdx.x;
  int n = t >> 5, q = t & 31;
  ((float4*)h)[t] = ((const float4*)emb)[(z[n]<<5) + q];
}

// ---------------- edge distances (PBC minimum image), pre-scaled t = r*1024/RMAX ----------------
__global__ __launch_bounds__(256) void k_geom(const int* __restrict__ ei,
    const float* __restrict__ pos, float* __restrict__ tsc){
  int e = blockIdx.x*256 + threadIdx.x;
  if (e >= N_EDGES) return;
  int a = ei[e], b = ei[N_EDGES + e];
  float dx = pos[3*a+0] - pos[3*b+0];
  float dy = pos[3*a+1] - pos[3*b+1];
  float dz = pos[3*a+2] - pos[3*b+2];
  dx -= rintf(dx*0.2f)*5.0f;
  dy -= rintf(dy*0.2f)*5.0f;
  dz -= rintf(dz*0.2f)*5.0f;
  float r = sqrtf(fmaf(dx,dx,fmaf(dy,dy,dz*dz)));
  tsc[e] = r * (1024.0f/RMAXF);
}

// ---------------- per-layer filter tables: 4 rows/block, split-k across 2 halves ----------------
#define TAB_R  4
#define TAB_NB 257   // ceil(1025/4)
__global__ __launch_bounds__(256) void k_tab(const float* __restrict__ w1, const float* __restrict__ b1,
      const float* __restrict__ w2, const float* __restrict__ b2, float* __restrict__ tab){
  __shared__ float ea[TAB_R][52];
  __shared__ float sT[TAB_R][HDIM];
  __shared__ float part[2][TAB_R][HDIM];
  int l  = blockIdx.x / TAB_NB;
  int i0 = (blockIdx.x % TAB_NB) * TAB_R;
  int tid = threadIdx.x;
  int j    = tid & 127;
  int half = tid >> 7;
  const float* w1l = w1 + (size_t)l*NG50*HDIM;
  const float* w2l = w2 + (size_t)l*HDIM*HDIM;
  float* tabl = tab + (size_t)l*TROWS*HDIM;
  const float STEP = RMAXF/1024.0f;
  const float GS   = 10.0f/49.0f;
  const float GC   = -0.5f/(GS*GS);
  if (tid < TAB_R*NG50){
    int rr = tid / NG50, k = tid - rr*NG50;
    int ri = i0 + rr; if (ri > TROWS-1) ri = TROWS-1;
    float d = ri*STEP - k*GS;
    ea[rr][k] = __expf(GC*d*d);
  }
  __syncthreads();
  {
    float acc[TAB_R] = {0,0,0,0};
    int kb = half*25;
    for (int k=0;k<25;++k){
      float wv = w1l[(kb+k)*HDIM + j];
      #pragma unroll
      for (int r=0;r<TAB_R;++r) acc[r] = fmaf(ea[r][kb+k], wv, acc[r]);
    }
    #pragma unroll
    for (int r=0;r<TAB_R;++r) part[half][r][j] = acc[r];
  }
  __syncthreads();
  {
    float b1v = b1[(size_t)l*HDIM + j];
    #pragma unroll
    for (int rr=0;rr<2;++rr){
      int r = half*2 + rr;
      sT[r][j] = ssp_f(part[0][r][j] + part[1][r][j] + b1v);
    }
  }
  __syncthreads();
  {
    float o[TAB_R] = {0,0,0,0};
    int kb = half*64;
    #pragma unroll 4
    for (int k=0;k<64;++k){
      float wv = w2l[(kb+k)*HDIM + j];
      #pragma unroll
      for (int r=0;r<TAB_R;++r) o[r] = fmaf(sT[r][kb+k], wv, o[r]);
    }
    #pragma unroll
    for (int r=0;r<TAB_R;++r) part[half][r][j] = o[r];
  }
  __syncthreads();
  {
    float b2v = b2[(size_t)l*HDIM + j];
    #pragma unroll
    for (int rr=0;rr<2;++rr){
      int r = half*2 + rr;
      int ri = i0 + r;
      if (ri < TROWS){
        float rv = ri*STEP;
        float C = 0.5f*(cosf(rv*0.31415926535897931f) + 1.0f);
        tabl[(size_t)ri*HDIM + j] = (part[0][r][j] + part[1][r][j] + b2v)*C;
      }
    }
  }
}

// ---------------- pack lerp pairs as bf16 ----------------
__global__ __launch_bounds__(256) void k_pack(const float* __restrict__ tab, ushort4* __restrict__ tabp){
  size_t t = (size_t)blockIdx.x*256 + threadIdx.x;   // over 6*1024*64
  int lane = (int)(t & 63);
  size_t row = t >> 6;                                // l*1024 + i
  size_t l = row >> 10, i = row & 1023;
  const float* a = tab + (l*TROWS + i)*HDIM + lane*2;
  float2 av = *(const float2*)a;
  float2 bv = *(const float2*)(a + HDIM);
  ushort4 p;
  p.x = f2bf(av.x); p.y = f2bf(av.y); p.z = f2bf(bv.x); p.w = f2bf(bv.y);
  tabp[t] = p;
}

// ---------------- CSR build ----------------
__global__ __launch_bounds__(256) void k_hist(const int* __restrict__ ei, int* __restrict__ cursor){
  int e = blockIdx.x*256 + threadIdx.x;
  if (e < N_EDGES) atomicAdd(&cursor[ei[N_EDGES + e]], 1);
}
__global__ __launch_bounds__(1024) void k_scan(int* __restrict__ cursor, int* __restrict__ rowptr){
  __shared__ int sbuf[1024];
  int t = threadIdx.x;
  int base = t*16;
  int d[16]; int s = 0;
  #pragma unroll
  for (int i=0;i<16;++i){ d[i] = cursor[base+i]; s += d[i]; }
  sbuf[t] = s; __syncthreads();
  for (int off=1; off<1024; off<<=1){
    int v = sbuf[t];
    int add = (t >= off) ? sbuf[t-off] : 0;
    __syncthreads();
    sbuf[t] = v + add;
    __syncthreads();
  }
  int run = (t==0) ? 0 : sbuf[t-1];
  #pragma unroll
  for (int i=0;i<16;++i){ rowptr[base+i] = run; cursor[base+i] = run; run += d[i]; }
  if (t==1023) rowptr[N_NODES] = run;
}
__global__ __launch_bounds__(256) void k_fill(const int* __restrict__ ei, const float* __restrict__ tsc,
    int* __restrict__ cursor, int* __restrict__ srcl, float* __restrict__ tl){
  int e = blockIdx.x*256 + threadIdx.x;
  if (e < N_EDGES){
    int c = ei[N_EDGES + e];
    int slot = atomicAdd(&cursor[c], 1);
    srcl[slot] = ei[e];
    tl[slot]   = tsc[e];
  }
}

// ---------------- xh(bf16) = h @ cf_w1[0], FR=16 rows/block, LDS-staged B ----------------
#define FR 16
__global__ __launch_bounds__(256,4) void k_gemm_xh(const float* __restrict__ A,
    const float* __restrict__ B, ushort4* __restrict__ Cb){
  __shared__ float Bs[32*HDIM];
  int tid = threadIdx.x;
  int m0 = blockIdx.x*FR;
  int tc = tid & 31, tr = tid >> 5;
  int j0 = tc*4;
  int lr0 = tr*2, lr1 = tr*2+1;
  float4 acc0 = make_float4(0,0,0,0), acc1 = acc0;
  const float* A0 = A + (size_t)(m0 + lr0)*HDIM;
  const float* A1 = A + (size_t)(m0 + lr1)*HDIM;
  for (int kc=0; kc<HDIM; kc+=32){
    __syncthreads();
    load_chunk(Bs, B, kc, tid);
    __syncthreads();
    #pragma unroll
    for (int kk=0; kk<32; kk+=4){
      float4 b0 = *(const float4*)(Bs + (kk+0)*HDIM + j0);
      float4 b1 = *(const float4*)(Bs + (kk+1)*HDIM + j0);
      float4 b2 = *(const float4*)(Bs + (kk+2)*HDIM + j0);
      float4 b3 = *(const float4*)(Bs + (kk+3)*HDIM + j0);
      float4 a0 = *(const float4*)(A0 + kc + kk);
      float4 a1 = *(const float4*)(A1 + kc + kk);
      fma4(acc0,a0.x,b0); fma4(acc0,a0.y,b1); fma4(acc0,a0.z,b2); fma4(acc0,a0.w,b3);
      fma4(acc1,a1.x,b0); fma4(acc1,a1.y,b1); fma4(acc1,a1.z,b2); fma4(acc1,a1.w,b3);
    }
  }
  ushort4 o;
  o.x=f2bf(acc0.x); o.y=f2bf(acc0.y); o.z=f2bf(acc0.z); o.w=f2bf(acc0.w);
  Cb[(size_t)(m0 + lr0)*32 + tc] = o;
  o.x=f2bf(acc1.x); o.y=f2bf(acc1.y); o.z=f2bf(acc1.z); o.w=f2bf(acc1.w);
  Cb[(size_t)(m0 + lr1)*32 + tc] = o;
}

// ---------------- edge aggregation: one wave per dst node, bf16, 8-edge unroll ----------------
#define AGG_EDGE(rr, tt) { \
  int ii = (int)tt; if (ii > 1023) ii = 1023; \
  float fr_ = tt - (float)ii; \
  ushort4 p_ = tabl[(size_t)ii*64]; \
  ushort2 x_ = xh2[(size_t)rr*64]; \
  float ax_=bf2f(p_.x), ay_=bf2f(p_.y); \
  ax = fmaf(bf2f(x_.x), fmaf(fr_, bf2f(p_.z)-ax_, ax_), ax); \
  ay = fmaf(bf2f(x_.y), fmaf(fr_, bf2f(p_.w)-ay_, ay_), ay); }
__global__ __launch_bounds__(256) void k_agg(const int* __restrict__ rowptr,
    const int* __restrict__ srcl, const float* __restrict__ tl,
    const ushort4* __restrict__ tabp, const ushort2* __restrict__ xhb, float* __restrict__ agg){
  int c = blockIdx.x*4 + (threadIdx.x >> 6);
  int lane = threadIdx.x & 63;
  int beg = rowptr[c], end = rowptr[c+1];
  const ushort4* tabl = tabp + lane;
  const ushort2* xh2  = xhb + lane;
  float ax = 0.f, ay = 0.f;
  for (int k0 = beg; k0 < end; k0 += 64){
    int rem = end - k0;
    int cnt = rem < 64 ? rem : 64;
    int   s_l = 0; float t_l = 0.f;
    if (lane < cnt){ s_l = srcl[k0+lane]; t_l = tl[k0+lane]; }
    int j = 0;
    for (; j+7 < cnt; j += 8){
      int   r0 = __shfl(s_l, j,   64); float t0 = __shfl(t_l, j,   64);
      int   r1 = __shfl(s_l, j+1, 64); float t1 = __shfl(t_l, j+1, 64);
      int   r2 = __shfl(s_l, j+2, 64); float t2 = __shfl(t_l, j+2, 64);
      int   r3 = __shfl(s_l, j+3, 64); float t3 = __shfl(t_l, j+3, 64);
      int   r4 = __shfl(s_l, j+4, 64); float t4 = __shfl(t_l, j+4, 64);
      int   r5 = __shfl(s_l, j+5, 64); float t5 = __shfl(t_l, j+5, 64);
      int   r6 = __shfl(s_l, j+6, 64); float t6 = __shfl(t_l, j+6, 64);
      int   r7 = __shfl(s_l, j+7, 64); float t7 = __shfl(t_l, j+7, 64);
      AGG_EDGE(r0, t0); AGG_EDGE(r1, t1); AGG_EDGE(r2, t2); AGG_EDGE(r3, t3);
      AGG_EDGE(r4, t4); AGG_EDGE(r5, t5); AGG_EDGE(r6, t6); AGG_EDGE(r7, t7);
    }
    for (; j < cnt; ++j){
      int   r0 = __shfl(s_l, j, 64); float t0 = __shfl(t_l, j, 64);
      AGG_EDGE(r0, t0);
    }
  }
  ((float2*)(agg + (size_t)c*HDIM))[lane] = make_float2(ax, ay);
}

// ---------------- fused interaction (R11 version: FR=16, 24 KB LDS, 46 us measured) ----------------
template<bool LAST>
__global__ __launch_bounds__(256,6) void k_fused3(const float* __restrict__ Ain,
    const float* __restrict__ W2, const float* __restrict__ B2,
    const float* __restrict__ WL, const float* __restrict__ BL,
    float* __restrict__ Hio, const float* __restrict__ W1n, ushort4* __restrict__ Xout){
  __shared__ float Bs[32*HDIM];   // 16 KB weight chunk
  __shared__ float Ss[FR*HDIM];   // 8 KB, holds t then h'
  int tid = threadIdx.x;
  int m0 = blockIdx.x*FR;
  int tc = tid & 31, tr = tid >> 5;
  int j0 = tc*4;
  int lr0 = tr*2, lr1 = tr*2+1;
  float4 acc0, acc1;

  // ---- stage A: acc = agg @ W2 ----
  acc0 = make_float4(0,0,0,0); acc1 = acc0;
  {
    const float* A0 = Ain + (size_t)(m0 + lr0)*HDIM;
    const float* A1 = Ain + (size_t)(m0 + lr1)*HDIM;
    for (int kc=0; kc<HDIM; kc+=32){
      __syncthreads();
      load_chunk(Bs, W2, kc, tid);
      __syncthreads();
      #pragma unroll
      for (int kk=0; kk<32; kk+=4){
        float4 b0 = *(const float4*)(Bs + (kk+0)*HDIM + j0);
        float4 b1 = *(const float4*)(Bs + (kk+1)*HDIM + j0);
        float4 b2 = *(const float4*)(Bs + (kk+2)*HDIM + j0);
        float4 b3 = *(const float4*)(Bs + (kk+3)*HDIM + j0);
        float4 a0 = *(const float4*)(A0 + kc + kk);
        float4 a1 = *(const float4*)(A1 + kc + kk);
        fma4(acc0,a0.x,b0); fma4(acc0,a0.y,b1); fma4(acc0,a0.z,b2); fma4(acc0,a0.w,b3);
        fma4(acc1,a1.x,b0); fma4(acc1,a1.y,b1); fma4(acc1,a1.z,b2); fma4(acc1,a1.w,b3);
      }
    }
  }
  {
    float4 b2v = *(const float4*)(B2 + j0);
    float4 v;
    v.x=ssp_f(acc0.x+b2v.x); v.y=ssp_f(acc0.y+b2v.y); v.z=ssp_f(acc0.z+b2v.z); v.w=ssp_f(acc0.w+b2v.w);
    *(float4*)(Ss + lr0*HDIM + j0) = v;
    v.x=ssp_f(acc1.x+b2v.x); v.y=ssp_f(acc1.y+b2v.y); v.z=ssp_f(acc1.z+b2v.z); v.w=ssp_f(acc1.w+b2v.w);
    *(float4*)(Ss + lr1*HDIM + j0) = v;
  }

  // ---- stage B: acc = t @ WL ; h' = h + acc + bl ----
  acc0 = make_float4(0,0,0,0); acc1 = acc0;
  for (int kc=0; kc<HDIM; kc+=32){
    __syncthreads();
    load_chunk(Bs, WL, kc, tid);
    __syncthreads();
    #pragma unroll
    for (int kk=0; kk<32; kk+=4){
      float4 b0 = *(const float4*)(Bs + (kk+0)*HDIM + j0);
      float4 b1 = *(const float4*)(Bs + (kk+1)*HDIM + j0);
      float4 b2 = *(const float4*)(Bs + (kk+2)*HDIM + j0);
      float4 b3 = *(const float4*)(Bs + (kk+3)*HDIM + j0);
      float4 a0 = *(const float4*)(Ss + lr0*HDIM + kc + kk);
      float4 a1 = *(const float4*)(Ss + lr1*HDIM + kc + kk);
      fma4(acc0,a0.x,b0); fma4(acc0,a0.y,b1); fma4(acc0,a0.z,b2); fma4(acc0,a0.w,b3);
      fma4(acc1,a1.x,b0); fma4(acc1,a1.y,b1); fma4(acc1,a1.z,b2); fma4(acc1,a1.w,b3);
    }
  }
  __syncthreads();   // all stage-B reads of Ss done before overwrite with h'
  {
    float4 blv = *(const float4*)(BL + j0);
    float* H0 = Hio + (size_t)(m0 + lr0)*HDIM + j0;
    float* H1 = Hio + (size_t)(m0 + lr1)*HDIM + j0;
    float4 hv;
    hv = *(float4*)H0;
    hv.x += acc0.x+blv.x; hv.y += acc0.y+blv.y; hv.z += acc0.z+blv.z; hv.w += acc0.w+blv.w;
    *(float4*)H0 = hv; if (!LAST) *(float4*)(Ss + lr0*HDIM + j0) = hv;
    hv = *(float4*)H1;
    hv.x += acc1.x+blv.x; hv.y += acc1.y+blv.y; hv.z += acc1.z+blv.z; hv.w += acc1.w+blv.w;
    *(float4*)H1 = hv; if (!LAST) *(float4*)(Ss + lr1*HDIM + j0) = hv;
  }
  if (LAST) return;

  // ---- stage C: xh_next(bf16) = h' @ W1n ----
  acc0 = make_float4(0,0,0,0); acc1 = acc0;
  for (int kc=0; kc<HDIM; kc+=32){
    __syncthreads();   // orders h' Ss writes before Bs overwrite
    load_chunk(Bs, W1n, kc, tid);
    __syncthreads();
    #pragma unroll
    for (int kk=0; kk<32; kk+=4){
      float4 b0 = *(const float4*)(Bs + (kk+0)*HDIM + j0);
      float4 b1 = *(const float4*)(Bs + (kk+1)*HDIM + j0);
      float4 b2 = *(const float4*)(Bs + (kk+2)*HDIM + j0);
      float4 b3 = *(const float4*)(Bs + (kk+3)*HDIM + j0);
      float4 a0 = *(const float4*)(Ss + lr0*HDIM + kc + kk);
      float4 a1 = *(const float4*)(Ss + lr1*HDIM + kc + kk);
      fma4(acc0,a0.x,b0); fma4(acc0,a0.y,b1); fma4(acc0,a0.z,b2); fma4(acc0,a0.w,b3);
      fma4(acc1,a1.x,b0); fma4(acc1,a1.y,b1); fma4(acc1,a1.z,b2); fma4(acc1,a1.w,b3);
    }
  }
  ushort4 o;
  o.x=f2bf(acc0.x); o.y=f2bf(acc0.y); o.z=f2bf(acc0.z); o.w=f2bf(acc0.w);
  Xout[(size_t)(m0 + lr0)*32 + tc] = o;
  o.x=f2bf(acc1.x); o.y=f2bf(acc1.y); o.z=f2bf(acc1.z); o.w=f2bf(acc1.w);
  Xout[(size_t)(m0 + lr1)*32 + tc] = o;
}

// ---------------- output MLP: per-node scalar (no atomics) ----------------
__global__ __launch_bounds__(256) void k_outA(const float* __restrict__ h, const float* __restrict__ w1,
    const float* __restrict__ b1, const float* __restrict__ w2, const float* __restrict__ b2,
    float* __restrict__ nodeval){
  int node = blockIdx.x*4 + (threadIdx.x >> 6);
  int lane = threadIdx.x & 63;
  float acc = b1[lane];
  const float* hrow = h + (size_t)node*HDIM;
  #pragma unroll 4
  for (int k=0;k<HDIM;++k) acc = fmaf(hrow[k], w1[k*64 + lane], acc);
  float s = ssp_f(acc) * w2[lane];
  for (int off=32; off>0; off>>=1) s += __shfl_down(s, off, 64);
  if (lane == 0) nodeval[node] = s + b2[0];
}

// ---------------- graph readout ----------------
__global__ __launch_bounds__(256) void k_outB(const float* __restrict__ nodeval,
    const int* __restrict__ batch, float* __restrict__ out){
  __shared__ float sred[4];
  int g = blockIdx.x;
  int t = threadIdx.x;
  float s = 0.f;
  for (int n = t; n < N_NODES; n += 256)
    if (batch[n] == g) s += nodeval[n];
  for (int off=32; off>0; off>>=1) s += __shfl_down(s, off, 64);
  if ((t & 63) == 0) sred[t >> 6] = s;
  __syncthreads();
  if (t == 0){
    float tot = sred[0] + sred[1] + sred[2] + sred[3];
    out[g] = 1.0f/(1.0f + __expf(-tot));
  }
}

// ---------------- host ----------------
extern "C" void kernel_launch(void* const* d_in, const int* in_sizes, int n_in,
                              void* d_out, int out_size, void* d_ws, size_t ws_size,
                              hipStream_t stream){
  (void)in_sizes; (void)n_in; (void)out_size;
  const int*   z      = (const int*)  d_in[0];
  const float* pos    = (const float*)d_in[1];
  const int*   ei     = (const int*)  d_in[2];
  const int*   batch  = (const int*)  d_in[3];
  const float* emb    = (const float*)d_in[4];
  const float* mlp_w1 = (const float*)d_in[5];
  const float* mlp_b1 = (const float*)d_in[6];
  const float* mlp_w2 = (const float*)d_in[7];
  const float* mlp_b2 = (const float*)d_in[8];
  const float* cf_w1  = (const float*)d_in[9];
  const float* cf_w2  = (const float*)d_in[10];
  const float* cf_b2  = (const float*)d_in[11];
  const float* lin_w  = (const float*)d_in[12];
  const float* lin_b  = (const float*)d_in[13];
  const float* ow1    = (const float*)d_in[14];
  const float* ob1    = (const float*)d_in[15];
  const float* ow2    = (const float*)d_in[16];
  const float* ob2    = (const float*)d_in[17];

  char* wp = (char*)d_ws;
  size_t used = 0;
  auto alloc = [&](size_t bytes)->char*{
    char* p = wp + used;
    used += (bytes + 1023) & ~(size_t)1023;
    return p;
  };
  float*   tsc     = (float*)alloc((size_t)N_EDGES*4);
  float*   tab     = (float*)alloc((size_t)NLAYER*TROWS*HDIM*4);
  ushort4* tabp    = (ushort4*)alloc((size_t)NLAYER*1024*64*8);
  float*   h       = (float*)alloc((size_t)N_NODES*HDIM*4);
  ushort4* xhb     = (ushort4*)alloc((size_t)N_NODES*32*8);
  float*   agg     = (float*)alloc((size_t)N_NODES*HDIM*4);
  int*     rowptr  = (int*)  alloc((size_t)(N_NODES+1)*4);
  int*     cursor  = (int*)  alloc((size_t)N_NODES*4);
  int*     srcl    = (int*)  alloc((size_t)N_EDGES*4);
  float*   tl      = (float*)alloc((size_t)N_EDGES*4);
  float*   nodeval = (float*)alloc((size_t)N_NODES*4);
  if (used > ws_size) return;

  hipMemsetAsync(cursor, 0, (size_t)N_NODES*4, stream);

  k_init_h<<<N_NODES*32/256, 256, 0, stream>>>(z, emb, h);
  k_geom  <<<N_EDGES/256, 256, 0, stream>>>(ei, pos, tsc);
  k_tab   <<<NLAYER*TAB_NB, 256, 0, stream>>>(mlp_w1, mlp_b1, mlp_w2, mlp_b2, tab);
  k_pack  <<<NLAYER*1024*64/256, 256, 0, stream>>>(tab, tabp);
  k_hist  <<<N_EDGES/256, 256, 0, stream>>>(ei, cursor);
  k_scan  <<<1, 1024, 0, stream>>>(cursor, rowptr);
  k_fill  <<<N_EDGES/256, 256, 0, stream>>>(ei, tsc, cursor, srcl, tl);

  k_gemm_xh<<<N_NODES/FR, 256, 0, stream>>>(h, cf_w1, xhb);
  for (int l=0; l<NLAYER; ++l){
    k_agg<<<N_NODES/4, 256, 0, stream>>>(rowptr, srcl, tl,
                 tabp + (size_t)l*1024*64, (const ushort2*)xhb, agg);
    if (l < NLAYER-1){
      k_fused3<false><<<N_NODES/FR, 256, 0, stream>>>(agg,
                 cf_w2 + (size_t)l*HDIM*HDIM, cf_b2 + (size_t)l*HDIM,
                 lin_w + (size_t)l*HDIM*HDIM, lin_b + (size_t)l*HDIM, h,
                 cf_w1 + (size_t)(l+1)*HDIM*HDIM, xhb);
    } else {
      k_fused3<true><<<N_NODES/FR, 256, 0, stream>>>(agg,
                 cf_w2 + (size_t)l*HDIM*HDIM, cf_b2 + (size_t)l*HDIM,
                 lin_w + (size_t)l*HDIM*HDIM, lin_b + (size_t)l*HDIM, h,
                 nullptr, nullptr);
    }
  }
  k_outA  <<<N_NODES/4, 256, 0, stream>>>(h, ow1, ob1, ow2, ob2, nodeval);
  k_outB  <<<NGRAPH, 256, 0, stream>>>(nodeval, batch, (float*)d_out);
}

// Round 14
// 524.621 us; speedup vs baseline: 1.0781x; 1.0781x over previous
//
#include <hip/hip_runtime.h>
#include <math.h>

#define N_NODES 16384
#define N_EDGES 262144
#define HDIM    128
#define NG50    50
#define NLAYER  6
#define NGRAPH  16
#define TROWS   1025
#define RMAXF   4.34f

__device__ __forceinline__ float ssp_f(float x){
  return (x > 20.0f ? x : log1pf(__expf(x))) - 0.6931471805599453f;
}
__device__ __forceinline__ void fma4(float4& c, float a, const float4 b){
  c.x = fmaf(a,b.x,c.x); c.y = fmaf(a,b.y,c.y); c.z = fmaf(a,b.z,c.z); c.w = fmaf(a,b.w,c.w);
}
// bf16 helpers (RNE)
__device__ __forceinline__ unsigned short f2bf(float x){
  unsigned u = __float_as_uint(x);
  u += 0x7FFF + ((u>>16)&1);
  return (unsigned short)(u>>16);
}
__device__ __forceinline__ float bf2f(unsigned short u){
  return __uint_as_float(((unsigned)u)<<16);
}
// cooperative 32x128 fp32 chunk load, immediate global->LDS. HARD RULES (measured):
// (R8+R10) float4s live across __syncthreads() demote to scratch -> no reg prefetch.
// (R12) FR=32 tile (2 blocks/CU) loses to occupancy. FR=16 is ~90% of LDS wall.
// (R13) k_agg 8-edge unroll regresses ~40us; 4-edge is the optimum.
__device__ __forceinline__ void load_chunk(float* Bs, const float* W, int kc, int tid){
  const float4* src = (const float4*)(W + kc*HDIM);
  float4* dst = (float4*)Bs;
  #pragma unroll
  for (int i=0;i<4;++i) dst[tid + i*256] = src[tid + i*256];
}

// ---------------- h = emb[z] ----------------
__global__ __launch_bounds__(256) void k_init_h(const int* __restrict__ z,
    const float* __restrict__ emb, float* __restrict__ h){
  int t = blockIdx.x*256 + threadIdx.x;
  int n = t >> 5, q = t & 31;
  ((float4*)h)[t] = ((const float4*)emb)[(z[n]<<5) + q];
}

// ---------------- per-layer filter tables: 4 rows/block, split-k across 2 halves ----------------
#define TAB_R  4
#define TAB_NB 257   // ceil(1025/4)
__global__ __launch_bounds__(256) void k_tab(const float* __restrict__ w1, const float* __restrict__ b1,
      const float* __restrict__ w2, const float* __restrict__ b2, float* __restrict__ tab){
  __shared__ float ea[TAB_R][52];
  __shared__ float sT[TAB_R][HDIM];
  __shared__ float part[2][TAB_R][HDIM];
  int l  = blockIdx.x / TAB_NB;
  int i0 = (blockIdx.x % TAB_NB) * TAB_R;
  int tid = threadIdx.x;
  int j    = tid & 127;
  int half = tid >> 7;
  const float* w1l = w1 + (size_t)l*NG50*HDIM;
  const float* w2l = w2 + (size_t)l*HDIM*HDIM;
  float* tabl = tab + (size_t)l*TROWS*HDIM;
  const float STEP = RMAXF/1024.0f;
  const float GS   = 10.0f/49.0f;
  const float GC   = -0.5f/(GS*GS);
  if (tid < TAB_R*NG50){
    int rr = tid / NG50, k = tid - rr*NG50;
    int ri = i0 + rr; if (ri > TROWS-1) ri = TROWS-1;
    float d = ri*STEP - k*GS;
    ea[rr][k] = __expf(GC*d*d);
  }
  __syncthreads();
  {
    float acc[TAB_R] = {0,0,0,0};
    int kb = half*25;
    for (int k=0;k<25;++k){
      float wv = w1l[(kb+k)*HDIM + j];
      #pragma unroll
      for (int r=0;r<TAB_R;++r) acc[r] = fmaf(ea[r][kb+k], wv, acc[r]);
    }
    #pragma unroll
    for (int r=0;r<TAB_R;++r) part[half][r][j] = acc[r];
  }
  __syncthreads();
  {
    float b1v = b1[(size_t)l*HDIM + j];
    #pragma unroll
    for (int rr=0;rr<2;++rr){
      int r = half*2 + rr;
      sT[r][j] = ssp_f(part[0][r][j] + part[1][r][j] + b1v);
    }
  }
  __syncthreads();
  {
    float o[TAB_R] = {0,0,0,0};
    int kb = half*64;
    #pragma unroll 4
    for (int k=0;k<64;++k){
      float wv = w2l[(kb+k)*HDIM + j];
      #pragma unroll
      for (int r=0;r<TAB_R;++r) o[r] = fmaf(sT[r][kb+k], wv, o[r]);
    }
    #pragma unroll
    for (int r=0;r<TAB_R;++r) part[half][r][j] = o[r];
  }
  __syncthreads();
  {
    float b2v = b2[(size_t)l*HDIM + j];
    #pragma unroll
    for (int rr=0;rr<2;++rr){
      int r = half*2 + rr;
      int ri = i0 + r;
      if (ri < TROWS){
        float rv = ri*STEP;
        float C = 0.5f*(cosf(rv*0.31415926535897931f) + 1.0f);
        tabl[(size_t)ri*HDIM + j] = (part[0][r][j] + part[1][r][j] + b2v)*C;
      }
    }
  }
}

// ---------------- pack lerp pairs as bf16 ----------------
__global__ __launch_bounds__(256) void k_pack(const float* __restrict__ tab, ushort4* __restrict__ tabp){
  size_t t = (size_t)blockIdx.x*256 + threadIdx.x;   // over 6*1024*64
  int lane = (int)(t & 63);
  size_t row = t >> 6;                                // l*1024 + i
  size_t l = row >> 10, i = row & 1023;
  const float* a = tab + (l*TROWS + i)*HDIM + lane*2;
  float2 av = *(const float2*)a;
  float2 bv = *(const float2*)(a + HDIM);
  ushort4 p;
  p.x = f2bf(av.x); p.y = f2bf(av.y); p.z = f2bf(bv.x); p.w = f2bf(bv.y);
  tabp[t] = p;
}

// ---------------- CSR build ----------------
__global__ __launch_bounds__(256) void k_hist(const int* __restrict__ ei, int* __restrict__ cursor){
  int e = blockIdx.x*256 + threadIdx.x;
  if (e < N_EDGES) atomicAdd(&cursor[ei[N_EDGES + e]], 1);
}
__global__ __launch_bounds__(1024) void k_scan(int* __restrict__ cursor, int* __restrict__ rowptr){
  __shared__ int sbuf[1024];
  int t = threadIdx.x;
  int base = t*16;
  int d[16]; int s = 0;
  #pragma unroll
  for (int i=0;i<16;++i){ d[i] = cursor[base+i]; s += d[i]; }
  sbuf[t] = s; __syncthreads();
  for (int off=1; off<1024; off<<=1){
    int v = sbuf[t];
    int add = (t >= off) ? sbuf[t-off] : 0;
    __syncthreads();
    sbuf[t] = v + add;
    __syncthreads();
  }
  int run = (t==0) ? 0 : sbuf[t-1];
  #pragma unroll
  for (int i=0;i<16;++i){ rowptr[base+i] = run; cursor[base+i] = run; run += d[i]; }
  if (t==1023) rowptr[N_NODES] = run;
}
// k_fill now also computes the PBC distance inline (k_geom folded in, R14)
__global__ __launch_bounds__(256) void k_fill(const int* __restrict__ ei, const float* __restrict__ pos,
    int* __restrict__ cursor, int* __restrict__ srcl, float* __restrict__ tl){
  int e = blockIdx.x*256 + threadIdx.x;
  if (e < N_EDGES){
    int a = ei[e];
    int c = ei[N_EDGES + e];
    float dx = pos[3*a+0] - pos[3*c+0];
    float dy = pos[3*a+1] - pos[3*c+1];
    float dz = pos[3*a+2] - pos[3*c+2];
    dx -= rintf(dx*0.2f)*5.0f;
    dy -= rintf(dy*0.2f)*5.0f;
    dz -= rintf(dz*0.2f)*5.0f;
    float r = sqrtf(fmaf(dx,dx,fmaf(dy,dy,dz*dz)));
    int slot = atomicAdd(&cursor[c], 1);
    srcl[slot] = a;
    tl[slot]   = r * (1024.0f/RMAXF);
  }
}

// ---------------- xh(bf16) = h @ cf_w1[0], FR=16 rows/block, LDS-staged B ----------------
#define FR 16
__global__ __launch_bounds__(256,4) void k_gemm_xh(const float* __restrict__ A,
    const float* __restrict__ B, ushort4* __restrict__ Cb){
  __shared__ float Bs[32*HDIM];
  int tid = threadIdx.x;
  int m0 = blockIdx.x*FR;
  int tc = tid & 31, tr = tid >> 5;
  int j0 = tc*4;
  int lr0 = tr*2, lr1 = tr*2+1;
  float4 acc0 = make_float4(0,0,0,0), acc1 = acc0;
  const float* A0 = A + (size_t)(m0 + lr0)*HDIM;
  const float* A1 = A + (size_t)(m0 + lr1)*HDIM;
  for (int kc=0; kc<HDIM; kc+=32){
    __syncthreads();
    load_chunk(Bs, B, kc, tid);
    __syncthreads();
    #pragma unroll
    for (int kk=0; kk<32; kk+=4){
      float4 b0 = *(const float4*)(Bs + (kk+0)*HDIM + j0);
      float4 b1 = *(const float4*)(Bs + (kk+1)*HDIM + j0);
      float4 b2 = *(const float4*)(Bs + (kk+2)*HDIM + j0);
      float4 b3 = *(const float4*)(Bs + (kk+3)*HDIM + j0);
      float4 a0 = *(const float4*)(A0 + kc + kk);
      float4 a1 = *(const float4*)(A1 + kc + kk);
      fma4(acc0,a0.x,b0); fma4(acc0,a0.y,b1); fma4(acc0,a0.z,b2); fma4(acc0,a0.w,b3);
      fma4(acc1,a1.x,b0); fma4(acc1,a1.y,b1); fma4(acc1,a1.z,b2); fma4(acc1,a1.w,b3);
    }
  }
  ushort4 o;
  o.x=f2bf(acc0.x); o.y=f2bf(acc0.y); o.z=f2bf(acc0.z); o.w=f2bf(acc0.w);
  Cb[(size_t)(m0 + lr0)*32 + tc] = o;
  o.x=f2bf(acc1.x); o.y=f2bf(acc1.y); o.z=f2bf(acc1.z); o.w=f2bf(acc1.w);
  Cb[(size_t)(m0 + lr1)*32 + tc] = o;
}

// ---------------- edge aggregation: one wave per dst node, bf16, 4-edge unroll (R11 optimum) ----------------
__global__ __launch_bounds__(256) void k_agg(const int* __restrict__ rowptr,
    const int* __restrict__ srcl, const float* __restrict__ tl,
    const ushort4* __restrict__ tabp, const ushort2* __restrict__ xhb, float* __restrict__ agg){
  int c = blockIdx.x*4 + (threadIdx.x >> 6);
  int lane = threadIdx.x & 63;
  int beg = rowptr[c], end = rowptr[c+1];
  const ushort4* tabl = tabp + lane;
  const ushort2* xh2  = xhb + lane;
  float ax = 0.f, ay = 0.f;
  for (int k0 = beg; k0 < end; k0 += 64){
    int rem = end - k0;
    int cnt = rem < 64 ? rem : 64;
    int   s_l = 0; float t_l = 0.f;
    if (lane < cnt){ s_l = srcl[k0+lane]; t_l = tl[k0+lane]; }
    int j = 0;
    for (; j+3 < cnt; j += 4){
      int   r0 = __shfl(s_l, j,   64);
      float t0 = __shfl(t_l, j,   64);
      int   r1 = __shfl(s_l, j+1, 64);
      float t1 = __shfl(t_l, j+1, 64);
      int   r2 = __shfl(s_l, j+2, 64);
      float t2 = __shfl(t_l, j+2, 64);
      int   r3 = __shfl(s_l, j+3, 64);
      float t3 = __shfl(t_l, j+3, 64);
      int i00 = (int)t0; if (i00 > 1023) i00 = 1023;
      int i01 = (int)t1; if (i01 > 1023) i01 = 1023;
      int i02 = (int)t2; if (i02 > 1023) i02 = 1023;
      int i03 = (int)t3; if (i03 > 1023) i03 = 1023;
      float f0 = t0 - (float)i00;
      float f1 = t1 - (float)i01;
      float f2 = t2 - (float)i02;
      float f3 = t3 - (float)i03;
      ushort4 p0 = tabl[(size_t)i00*64];
      ushort4 p1 = tabl[(size_t)i01*64];
      ushort4 p2 = tabl[(size_t)i02*64];
      ushort4 p3 = tabl[(size_t)i03*64];
      ushort2 x0 = xh2[(size_t)r0*64];
      ushort2 x1 = xh2[(size_t)r1*64];
      ushort2 x2 = xh2[(size_t)r2*64];
      ushort2 x3 = xh2[(size_t)r3*64];
      float a0x=bf2f(p0.x), a0y=bf2f(p0.y), d0x=bf2f(p0.z)-a0x, d0y=bf2f(p0.w)-a0y;
      float a1x=bf2f(p1.x), a1y=bf2f(p1.y), d1x=bf2f(p1.z)-a1x, d1y=bf2f(p1.w)-a1y;
      float a2x=bf2f(p2.x), a2y=bf2f(p2.y), d2x=bf2f(p2.z)-a2x, d2y=bf2f(p2.w)-a2y;
      float a3x=bf2f(p3.x), a3y=bf2f(p3.y), d3x=bf2f(p3.z)-a3x, d3y=bf2f(p3.w)-a3y;
      ax = fmaf(bf2f(x0.x), fmaf(f0, d0x, a0x), ax);
      ay = fmaf(bf2f(x0.y), fmaf(f0, d0y, a0y), ay);
      ax = fmaf(bf2f(x1.x), fmaf(f1, d1x, a1x), ax);
      ay = fmaf(bf2f(x1.y), fmaf(f1, d1y, a1y), ay);
      ax = fmaf(bf2f(x2.x), fmaf(f2, d2x, a2x), ax);
      ay = fmaf(bf2f(x2.y), fmaf(f2, d2y, a2y), ay);
      ax = fmaf(bf2f(x3.x), fmaf(f3, d3x, a3x), ax);
      ay = fmaf(bf2f(x3.y), fmaf(f3, d3y, a3y), ay);
    }
    for (; j < cnt; ++j){
      int   r0 = __shfl(s_l, j, 64);
      float t0 = __shfl(t_l, j, 64);
      int i00 = (int)t0; if (i00 > 1023) i00 = 1023;
      float f0 = t0 - (float)i00;
      ushort4 p0 = tabl[(size_t)i00*64];
      ushort2 x0 = xh2[(size_t)r0*64];
      float a0x=bf2f(p0.x), a0y=bf2f(p0.y), d0x=bf2f(p0.z)-a0x, d0y=bf2f(p0.w)-a0y;
      ax = fmaf(bf2f(x0.x), fmaf(f0, d0x, a0x), ax);
      ay = fmaf(bf2f(x0.y), fmaf(f0, d0y, a0y), ay);
    }
  }
  ((float2*)(agg + (size_t)c*HDIM))[lane] = make_float2(ax, ay);
}

// ---------------- fused interaction (R11 version: FR=16, 24 KB LDS, 46 us measured) ----------------
template<bool LAST>
__global__ __launch_bounds__(256,6) void k_fused3(const float* __restrict__ Ain,
    const float* __restrict__ W2, const float* __restrict__ B2,
    const float* __restrict__ WL, const float* __restrict__ BL,
    float* __restrict__ Hio, const float* __restrict__ W1n, ushort4* __restrict__ Xout){
  __shared__ float Bs[32*HDIM];   // 16 KB weight chunk
  __shared__ float Ss[FR*HDIM];   // 8 KB, holds t then h'
  int tid = threadIdx.x;
  int m0 = blockIdx.x*FR;
  int tc = tid & 31, tr = tid >> 5;
  int j0 = tc*4;
  int lr0 = tr*2, lr1 = tr*2+1;
  float4 acc0, acc1;

  // ---- stage A: acc = agg @ W2 ----
  acc0 = make_float4(0,0,0,0); acc1 = acc0;
  {
    const float* A0 = Ain + (size_t)(m0 + lr0)*HDIM;
    const float* A1 = Ain + (size_t)(m0 + lr1)*HDIM;
    for (int kc=0; kc<HDIM; kc+=32){
      __syncthreads();
      load_chunk(Bs, W2, kc, tid);
      __syncthreads();
      #pragma unroll
      for (int kk=0; kk<32; kk+=4){
        float4 b0 = *(const float4*)(Bs + (kk+0)*HDIM + j0);
        float4 b1 = *(const float4*)(Bs + (kk+1)*HDIM + j0);
        float4 b2 = *(const float4*)(Bs + (kk+2)*HDIM + j0);
        float4 b3 = *(const float4*)(Bs + (kk+3)*HDIM + j0);
        float4 a0 = *(const float4*)(A0 + kc + kk);
        float4 a1 = *(const float4*)(A1 + kc + kk);
        fma4(acc0,a0.x,b0); fma4(acc0,a0.y,b1); fma4(acc0,a0.z,b2); fma4(acc0,a0.w,b3);
        fma4(acc1,a1.x,b0); fma4(acc1,a1.y,b1); fma4(acc1,a1.z,b2); fma4(acc1,a1.w,b3);
      }
    }
  }
  {
    float4 b2v = *(const float4*)(B2 + j0);
    float4 v;
    v.x=ssp_f(acc0.x+b2v.x); v.y=ssp_f(acc0.y+b2v.y); v.z=ssp_f(acc0.z+b2v.z); v.w=ssp_f(acc0.w+b2v.w);
    *(float4*)(Ss + lr0*HDIM + j0) = v;
    v.x=ssp_f(acc1.x+b2v.x); v.y=ssp_f(acc1.y+b2v.y); v.z=ssp_f(acc1.z+b2v.z); v.w=ssp_f(acc1.w+b2v.w);
    *(float4*)(Ss + lr1*HDIM + j0) = v;
  }

  // ---- stage B: acc = t @ WL ; h' = h + acc + bl ----
  acc0 = make_float4(0,0,0,0); acc1 = acc0;
  for (int kc=0; kc<HDIM; kc+=32){
    __syncthreads();
    load_chunk(Bs, WL, kc, tid);
    __syncthreads();
    #pragma unroll
    for (int kk=0; kk<32; kk+=4){
      float4 b0 = *(const float4*)(Bs + (kk+0)*HDIM + j0);
      float4 b1 = *(const float4*)(Bs + (kk+1)*HDIM + j0);
      float4 b2 = *(const float4*)(Bs + (kk+2)*HDIM + j0);
      float4 b3 = *(const float4*)(Bs + (kk+3)*HDIM + j0);
      float4 a0 = *(const float4*)(Ss + lr0*HDIM + kc + kk);
      float4 a1 = *(const float4*)(Ss + lr1*HDIM + kc + kk);
      fma4(acc0,a0.x,b0); fma4(acc0,a0.y,b1); fma4(acc0,a0.z,b2); fma4(acc0,a0.w,b3);
      fma4(acc1,a1.x,b0); fma4(acc1,a1.y,b1); fma4(acc1,a1.z,b2); fma4(acc1,a1.w,b3);
    }
  }
  __syncthreads();   // all stage-B reads of Ss done before overwrite with h'
  {
    float4 blv = *(const float4*)(BL + j0);
    float* H0 = Hio + (size_t)(m0 + lr0)*HDIM + j0;
    float* H1 = Hio + (size_t)(m0 + lr1)*HDIM + j0;
    float4 hv;
    hv = *(float4*)H0;
    hv.x += acc0.x+blv.x; hv.y += acc0.y+blv.y; hv.z += acc0.z+blv.z; hv.w += acc0.w+blv.w;
    *(float4*)H0 = hv; if (!LAST) *(float4*)(Ss + lr0*HDIM + j0) = hv;
    hv = *(float4*)H1;
    hv.x += acc1.x+blv.x; hv.y += acc1.y+blv.y; hv.z += acc1.z+blv.z; hv.w += acc1.w+blv.w;
    *(float4*)H1 = hv; if (!LAST) *(float4*)(Ss + lr1*HDIM + j0) = hv;
  }
  if (LAST) return;

  // ---- stage C: xh_next(bf16) = h' @ W1n ----
  acc0 = make_float4(0,0,0,0); acc1 = acc0;
  for (int kc=0; kc<HDIM; kc+=32){
    __syncthreads();   // orders h' Ss writes before Bs overwrite
    load_chunk(Bs, W1n, kc, tid);
    __syncthreads();
    #pragma unroll
    for (int kk=0; kk<32; kk+=4){
      float4 b0 = *(const float4*)(Bs + (kk+0)*HDIM + j0);
      float4 b1 = *(const float4*)(Bs + (kk+1)*HDIM + j0);
      float4 b2 = *(const float4*)(Bs + (kk+2)*HDIM + j0);
      float4 b3 = *(const float4*)(Bs + (kk+3)*HDIM + j0);
      float4 a0 = *(const float4*)(Ss + lr0*HDIM + kc + kk);
      float4 a1 = *(const float4*)(Ss + lr1*HDIM + kc + kk);
      fma4(acc0,a0.x,b0); fma4(acc0,a0.y,b1); fma4(acc0,a0.z,b2); fma4(acc0,a0.w,b3);
      fma4(acc1,a1.x,b0); fma4(acc1,a1.y,b1); fma4(acc1,a1.z,b2); fma4(acc1,a1.w,b3);
    }
  }
  ushort4 o;
  o.x=f2bf(acc0.x); o.y=f2bf(acc0.y); o.z=f2bf(acc0.z); o.w=f2bf(acc0.w);
  Xout[(size_t)(m0 + lr0)*32 + tc] = o;
  o.x=f2bf(acc1.x); o.y=f2bf(acc1.y); o.z=f2bf(acc1.z); o.w=f2bf(acc1.w);
  Xout[(size_t)(m0 + lr1)*32 + tc] = o;
}

// ---------------- output MLP: per-node scalar (no atomics) ----------------
__global__ __launch_bounds__(256) void k_outA(const float* __restrict__ h, const float* __restrict__ w1,
    const float* __restrict__ b1, const float* __restrict__ w2, const float* __restrict__ b2,
    float* __restrict__ nodeval){
  int node = blockIdx.x*4 + (threadIdx.x >> 6);
  int lane = threadIdx.x & 63;
  float acc = b1[lane];
  const float* hrow = h + (size_t)node*HDIM;
  #pragma unroll 4
  for (int k=0;k<HDIM;++k) acc = fmaf(hrow[k], w1[k*64 + lane], acc);
  float s = ssp_f(acc) * w2[lane];
  for (int off=32; off>0; off>>=1) s += __shfl_down(s, off, 64);
  if (lane == 0) nodeval[node] = s + b2[0];
}

// ---------------- graph readout ----------------
__global__ __launch_bounds__(256) void k_outB(const float* __restrict__ nodeval,
    const int* __restrict__ batch, float* __restrict__ out){
  __shared__ float sred[4];
  int g = blockIdx.x;
  int t = threadIdx.x;
  float s = 0.f;
  for (int n = t; n < N_NODES; n += 256)
    if (batch[n] == g) s += nodeval[n];
  for (int off=32; off>0; off>>=1) s += __shfl_down(s, off, 64);
  if ((t & 63) == 0) sred[t >> 6] = s;
  __syncthreads();
  if (t == 0){
    float tot = sred[0] + sred[1] + sred[2] + sred[3];
    out[g] = 1.0f/(1.0f + __expf(-tot));
  }
}

// ---------------- host ----------------
extern "C" void kernel_launch(void* const* d_in, const int* in_sizes, int n_in,
                              void* d_out, int out_size, void* d_ws, size_t ws_size,
                              hipStream_t stream){
  (void)in_sizes; (void)n_in; (void)out_size;
  const int*   z      = (const int*)  d_in[0];
  const float* pos    = (const float*)d_in[1];
  const int*   ei     = (const int*)  d_in[2];
  const int*   batch  = (const int*)  d_in[3];
  const float* emb    = (const float*)d_in[4];
  const float* mlp_w1 = (const float*)d_in[5];
  const float* mlp_b1 = (const float*)d_in[6];
  const float* mlp_w2 = (const float*)d_in[7];
  const float* mlp_b2 = (const float*)d_in[8];
  const float* cf_w1  = (const float*)d_in[9];
  const float* cf_w2  = (const float*)d_in[10];
  const float* cf_b2  = (const float*)d_in[11];
  const float* lin_w  = (const float*)d_in[12];
  const float* lin_b  = (const float*)d_in[13];
  const float* ow1    = (const float*)d_in[14];
  const float* ob1    = (const float*)d_in[15];
  const float* ow2    = (const float*)d_in[16];
  const float* ob2    = (const float*)d_in[17];

  char* wp = (char*)d_ws;
  size_t used = 0;
  auto alloc = [&](size_t bytes)->char*{
    char* p = wp + used;
    used += (bytes + 1023) & ~(size_t)1023;
    return p;
  };
  float*   tab     = (float*)alloc((size_t)NLAYER*TROWS*HDIM*4);
  ushort4* tabp    = (ushort4*)alloc((size_t)NLAYER*1024*64*8);
  float*   h       = (float*)alloc((size_t)N_NODES*HDIM*4);
  ushort4* xhb     = (ushort4*)alloc((size_t)N_NODES*32*8);
  float*   agg     = (float*)alloc((size_t)N_NODES*HDIM*4);
  int*     rowptr  = (int*)  alloc((size_t)(N_NODES+1)*4);
  int*     cursor  = (int*)  alloc((size_t)N_NODES*4);
  int*     srcl    = (int*)  alloc((size_t)N_EDGES*4);
  float*   tl      = (float*)alloc((size_t)N_EDGES*4);
  float*   nodeval = (float*)alloc((size_t)N_NODES*4);
  if (used > ws_size) return;

  hipMemsetAsync(cursor, 0, (size_t)N_NODES*4, stream);

  k_init_h<<<N_NODES*32/256, 256, 0, stream>>>(z, emb, h);
  k_tab   <<<NLAYER*TAB_NB, 256, 0, stream>>>(mlp_w1, mlp_b1, mlp_w2, mlp_b2, tab);
  k_pack  <<<NLAYER*1024*64/256, 256, 0, stream>>>(tab, tabp);
  k_hist  <<<N_EDGES/256, 256, 0, stream>>>(ei, cursor);
  k_scan  <<<1, 1024, 0, stream>>>(cursor, rowptr);
  k_fill  <<<N_EDGES/256, 256, 0, stream>>>(ei, pos, cursor, srcl, tl);

  k_gemm_xh<<<N_NODES/FR, 256, 0, stream>>>(h, cf_w1, xhb);
  for (int l=0; l<NLAYER; ++l){
    k_agg<<<N_NODES/4, 256, 0, stream>>>(rowptr, srcl, tl,
                 tabp + (size_t)l*1024*64, (const ushort2*)xhb, agg);
    if (l < NLAYER-1){
      k_fused3<false><<<N_NODES/FR, 256, 0, stream>>>(agg,
                 cf_w2 + (size_t)l*HDIM*HDIM, cf_b2 + (size_t)l*HDIM,
                 lin_w + (size_t)l*HDIM*HDIM, lin_b + (size_t)l*HDIM, h,
                 cf_w1 + (size_t)(l+1)*HDIM*HDIM, xhb);
    } else {
      k_fused3<true><<<N_NODES/FR, 256, 0, stream>>>(agg,
                 cf_w2 + (size_t)l*HDIM*HDIM, cf_b2 + (size_t)l*HDIM,
                 lin_w + (size_t)l*HDIM*HDIM, lin_b + (size_t)l*HDIM, h,
                 nullptr, nullptr);
    }
  }
  k_outA  <<<N_NODES/4, 256, 0, stream>>>(h, ow1, ob1, ow2, ob2, nodeval);
  k_outB  <<<NGRAPH, 256, 0, stream>>>(nodeval, batch, (float*)d_out);
}

// Round 15
// 511.295 us; speedup vs baseline: 1.1062x; 1.0261x over previous
//
#include <hip/hip_runtime.h>
#include <math.h>

#define N_NODES 16384
#define N_EDGES 262144
#define HDIM    128
#define NG50    50
#define NLAYER  6
#define NGRAPH  16
#define TROWS   1025
#define RMAXF   4.34f

__device__ __forceinline__ float ssp_f(float x){
  return (x > 20.0f ? x : log1pf(__expf(x))) - 0.6931471805599453f;
}
__device__ __forceinline__ void fma4(float4& c, float a, const float4 b){
  c.x = fmaf(a,b.x,c.x); c.y = fmaf(a,b.y,c.y); c.z = fmaf(a,b.z,c.z); c.w = fmaf(a,b.w,c.w);
}
// bf16 helpers (RNE)
__device__ __forceinline__ unsigned short f2bf(float x){
  unsigned u = __float_as_uint(x);
  u += 0x7FFF + ((u>>16)&1);
  return (unsigned short)(u>>16);
}
__device__ __forceinline__ float bf2f(unsigned short u){
  return __uint_as_float(((unsigned)u)<<16);
}
// plain cooperative chunk load (k_gemm_xh keeps this)
__device__ __forceinline__ void load_chunk(float* Bs, const float* W, int kc, int tid){
  const float4* src = (const float4*)(W + kc*HDIM);
  float4* dst = (float4*)Bs;
  #pragma unroll
  for (int i=0;i<4;++i) dst[tid + i*256] = src[tid + i*256];
}
// async global->LDS DMA staging of one 32x128 fp32 chunk (16 KB).
// Zero VGPR temporaries -> structurally immune to the R8/R10 scratch-spill.
// HW computes lds dest = wave-uniform base + lane*16 (guide m97/m104).
typedef const __attribute__((address_space(1))) unsigned int* gp_t;
typedef __attribute__((address_space(3))) unsigned int* lp_t;
__device__ __forceinline__ void stage_dma(float* BsDst, const float* W, int kc, int tid){
  const float4* g = (const float4*)(W + kc*HDIM);
  float4* l = (float4*)BsDst;
  int lane  = tid & 63;
  int wbase = tid & 192;          // (tid>>6)*64
  #pragma unroll
  for (int i=0;i<4;++i){
    int base = i*256 + wbase;
    __builtin_amdgcn_global_load_lds((gp_t)(const void*)(g + base + lane),
                                     (lp_t)(void*)(l + base), 16, 0, 0);
  }
}

// ---------------- h = emb[z] ----------------
__global__ __launch_bounds__(256) void k_init_h(const int* __restrict__ z,
    const float* __restrict__ emb, float* __restrict__ h){
  int t = blockIdx.x*256 + threadIdx.x;
  int n = t >> 5, q = t & 31;
  ((float4*)h)[t] = ((const float4*)emb)[(z[n]<<5) + q];
}

// ---------------- per-layer filter tables: 4 rows/block, split-k ----------------
#define TAB_R  4
#define TAB_NB 257   // ceil(1025/4)
__global__ __launch_bounds__(256) void k_tab(const float* __restrict__ w1, const float* __restrict__ b1,
      const float* __restrict__ w2, const float* __restrict__ b2, float* __restrict__ tab){
  __shared__ float ea[TAB_R][52];
  __shared__ float sT[TAB_R][HDIM];
  __shared__ float part[2][TAB_R][HDIM];
  int l  = blockIdx.x / TAB_NB;
  int i0 = (blockIdx.x % TAB_NB) * TAB_R;
  int tid = threadIdx.x;
  int j    = tid & 127;
  int half = tid >> 7;
  const float* w1l = w1 + (size_t)l*NG50*HDIM;
  const float* w2l = w2 + (size_t)l*HDIM*HDIM;
  float* tabl = tab + (size_t)l*TROWS*HDIM;
  const float STEP = RMAXF/1024.0f;
  const float GS   = 10.0f/49.0f;
  const float GC   = -0.5f/(GS*GS);
  if (tid < TAB_R*NG50){
    int rr = tid / NG50, k = tid - rr*NG50;
    int ri = i0 + rr; if (ri > TROWS-1) ri = TROWS-1;
    float d = ri*STEP - k*GS;
    ea[rr][k] = __expf(GC*d*d);
  }
  __syncthreads();
  {
    float acc[TAB_R] = {0,0,0,0};
    int kb = half*25;
    for (int k=0;k<25;++k){
      float wv = w1l[(kb+k)*HDIM + j];
      #pragma unroll
      for (int r=0;r<TAB_R;++r) acc[r] = fmaf(ea[r][kb+k], wv, acc[r]);
    }
    #pragma unroll
    for (int r=0;r<TAB_R;++r) part[half][r][j] = acc[r];
  }
  __syncthreads();
  {
    float b1v = b1[(size_t)l*HDIM + j];
    #pragma unroll
    for (int rr=0;rr<2;++rr){
      int r = half*2 + rr;
      sT[r][j] = ssp_f(part[0][r][j] + part[1][r][j] + b1v);
    }
  }
  __syncthreads();
  {
    float o[TAB_R] = {0,0,0,0};
    int kb = half*64;
    #pragma unroll 4
    for (int k=0;k<64;++k){
      float wv = w2l[(kb+k)*HDIM + j];
      #pragma unroll
      for (int r=0;r<TAB_R;++r) o[r] = fmaf(sT[r][kb+k], wv, o[r]);
    }
    #pragma unroll
    for (int r=0;r<TAB_R;++r) part[half][r][j] = o[r];
  }
  __syncthreads();
  {
    float b2v = b2[(size_t)l*HDIM + j];
    #pragma unroll
    for (int rr=0;rr<2;++rr){
      int r = half*2 + rr;
      int ri = i0 + r;
      if (ri < TROWS){
        float rv = ri*STEP;
        float C = 0.5f*(cosf(rv*0.31415926535897931f) + 1.0f);
        tabl[(size_t)ri*HDIM + j] = (part[0][r][j] + part[1][r][j] + b2v)*C;
      }
    }
  }
}

// ---------------- pack lerp pairs as bf16 ----------------
__global__ __launch_bounds__(256) void k_pack(const float* __restrict__ tab, ushort4* __restrict__ tabp){
  size_t t = (size_t)blockIdx.x*256 + threadIdx.x;
  int lane = (int)(t & 63);
  size_t row = t >> 6;
  size_t l = row >> 10, i = row & 1023;
  const float* a = tab + (l*TROWS + i)*HDIM + lane*2;
  float2 av = *(const float2*)a;
  float2 bv = *(const float2*)(a + HDIM);
  ushort4 p;
  p.x = f2bf(av.x); p.y = f2bf(av.y); p.z = f2bf(bv.x); p.w = f2bf(bv.y);
  tabp[t] = p;
}

// ---------------- CSR build ----------------
__global__ __launch_bounds__(256) void k_hist(const int* __restrict__ ei, int* __restrict__ cursor){
  int e = blockIdx.x*256 + threadIdx.x;
  if (e < N_EDGES) atomicAdd(&cursor[ei[N_EDGES + e]], 1);
}
__global__ __launch_bounds__(1024) void k_scan(int* __restrict__ cursor, int* __restrict__ rowptr){
  __shared__ int sbuf[1024];
  int t = threadIdx.x;
  int base = t*16;
  int d[16]; int s = 0;
  #pragma unroll
  for (int i=0;i<16;++i){ d[i] = cursor[base+i]; s += d[i]; }
  sbuf[t] = s; __syncthreads();
  for (int off=1; off<1024; off<<=1){
    int v = sbuf[t];
    int add = (t >= off) ? sbuf[t-off] : 0;
    __syncthreads();
    sbuf[t] = v + add;
    __syncthreads();
  }
  int run = (t==0) ? 0 : sbuf[t-1];
  #pragma unroll
  for (int i=0;i<16;++i){ rowptr[base+i] = run; cursor[base+i] = run; run += d[i]; }
  if (t==1023) rowptr[N_NODES] = run;
}
__global__ __launch_bounds__(256) void k_fill(const int* __restrict__ ei, const float* __restrict__ pos,
    int* __restrict__ cursor, int* __restrict__ srcl, float* __restrict__ tl){
  int e = blockIdx.x*256 + threadIdx.x;
  if (e < N_EDGES){
    int a = ei[e];
    int c = ei[N_EDGES + e];
    float dx = pos[3*a+0] - pos[3*c+0];
    float dy = pos[3*a+1] - pos[3*c+1];
    float dz = pos[3*a+2] - pos[3*c+2];
    dx -= rintf(dx*0.2f)*5.0f;
    dy -= rintf(dy*0.2f)*5.0f;
    dz -= rintf(dz*0.2f)*5.0f;
    float r = sqrtf(fmaf(dx,dx,fmaf(dy,dy,dz*dz)));
    int slot = atomicAdd(&cursor[c], 1);
    srcl[slot] = a;
    tl[slot]   = r * (1024.0f/RMAXF);
  }
}

// ---------------- xh(bf16) = h @ cf_w1[0] (unchanged R14 version) ----------------
#define FR 16
__global__ __launch_bounds__(256,4) void k_gemm_xh(const float* __restrict__ A,
    const float* __restrict__ B, ushort4* __restrict__ Cb){
  __shared__ float Bs[32*HDIM];
  int tid = threadIdx.x;
  int m0 = blockIdx.x*FR;
  int tc = tid & 31, tr = tid >> 5;
  int j0 = tc*4;
  int lr0 = tr*2, lr1 = tr*2+1;
  float4 acc0 = make_float4(0,0,0,0), acc1 = acc0;
  const float* A0 = A + (size_t)(m0 + lr0)*HDIM;
  const float* A1 = A + (size_t)(m0 + lr1)*HDIM;
  for (int kc=0; kc<HDIM; kc+=32){
    __syncthreads();
    load_chunk(Bs, B, kc, tid);
    __syncthreads();
    #pragma unroll
    for (int kk=0; kk<32; kk+=4){
      float4 b0 = *(const float4*)(Bs + (kk+0)*HDIM + j0);
      float4 b1 = *(const float4*)(Bs + (kk+1)*HDIM + j0);
      float4 b2 = *(const float4*)(Bs + (kk+2)*HDIM + j0);
      float4 b3 = *(const float4*)(Bs + (kk+3)*HDIM + j0);
      float4 a0 = *(const float4*)(A0 + kc + kk);
      float4 a1 = *(const float4*)(A1 + kc + kk);
      fma4(acc0,a0.x,b0); fma4(acc0,a0.y,b1); fma4(acc0,a0.z,b2); fma4(acc0,a0.w,b3);
      fma4(acc1,a1.x,b0); fma4(acc1,a1.y,b1); fma4(acc1,a1.z,b2); fma4(acc1,a1.w,b3);
    }
  }
  ushort4 o;
  o.x=f2bf(acc0.x); o.y=f2bf(acc0.y); o.z=f2bf(acc0.z); o.w=f2bf(acc0.w);
  Cb[(size_t)(m0 + lr0)*32 + tc] = o;
  o.x=f2bf(acc1.x); o.y=f2bf(acc1.y); o.z=f2bf(acc1.z); o.w=f2bf(acc1.w);
  Cb[(size_t)(m0 + lr1)*32 + tc] = o;
}

// ---------------- edge aggregation (R11 optimum: 4-edge unroll) ----------------
__global__ __launch_bounds__(256) void k_agg(const int* __restrict__ rowptr,
    const int* __restrict__ srcl, const float* __restrict__ tl,
    const ushort4* __restrict__ tabp, const ushort2* __restrict__ xhb, float* __restrict__ agg){
  int c = blockIdx.x*4 + (threadIdx.x >> 6);
  int lane = threadIdx.x & 63;
  int beg = rowptr[c], end = rowptr[c+1];
  const ushort4* tabl = tabp + lane;
  const ushort2* xh2  = xhb + lane;
  float ax = 0.f, ay = 0.f;
  for (int k0 = beg; k0 < end; k0 += 64){
    int rem = end - k0;
    int cnt = rem < 64 ? rem : 64;
    int   s_l = 0; float t_l = 0.f;
    if (lane < cnt){ s_l = srcl[k0+lane]; t_l = tl[k0+lane]; }
    int j = 0;
    for (; j+3 < cnt; j += 4){
      int   r0 = __shfl(s_l, j,   64);
      float t0 = __shfl(t_l, j,   64);
      int   r1 = __shfl(s_l, j+1, 64);
      float t1 = __shfl(t_l, j+1, 64);
      int   r2 = __shfl(s_l, j+2, 64);
      float t2 = __shfl(t_l, j+2, 64);
      int   r3 = __shfl(s_l, j+3, 64);
      float t3 = __shfl(t_l, j+3, 64);
      int i00 = (int)t0; if (i00 > 1023) i00 = 1023;
      int i01 = (int)t1; if (i01 > 1023) i01 = 1023;
      int i02 = (int)t2; if (i02 > 1023) i02 = 1023;
      int i03 = (int)t3; if (i03 > 1023) i03 = 1023;
      float f0 = t0 - (float)i00;
      float f1 = t1 - (float)i01;
      float f2 = t2 - (float)i02;
      float f3 = t3 - (float)i03;
      ushort4 p0 = tabl[(size_t)i00*64];
      ushort4 p1 = tabl[(size_t)i01*64];
      ushort4 p2 = tabl[(size_t)i02*64];
      ushort4 p3 = tabl[(size_t)i03*64];
      ushort2 x0 = xh2[(size_t)r0*64];
      ushort2 x1 = xh2[(size_t)r1*64];
      ushort2 x2 = xh2[(size_t)r2*64];
      ushort2 x3 = xh2[(size_t)r3*64];
      float a0x=bf2f(p0.x), a0y=bf2f(p0.y), d0x=bf2f(p0.z)-a0x, d0y=bf2f(p0.w)-a0y;
      float a1x=bf2f(p1.x), a1y=bf2f(p1.y), d1x=bf2f(p1.z)-a1x, d1y=bf2f(p1.w)-a1y;
      float a2x=bf2f(p2.x), a2y=bf2f(p2.y), d2x=bf2f(p2.z)-a2x, d2y=bf2f(p2.w)-a2y;
      float a3x=bf2f(p3.x), a3y=bf2f(p3.y), d3x=bf2f(p3.z)-a3x, d3y=bf2f(p3.w)-a3y;
      ax = fmaf(bf2f(x0.x), fmaf(f0, d0x, a0x), ax);
      ay = fmaf(bf2f(x0.y), fmaf(f0, d0y, a0y), ay);
      ax = fmaf(bf2f(x1.x), fmaf(f1, d1x, a1x), ax);
      ay = fmaf(bf2f(x1.y), fmaf(f1, d1y, a1y), ay);
      ax = fmaf(bf2f(x2.x), fmaf(f2, d2x, a2x), ax);
      ay = fmaf(bf2f(x2.y), fmaf(f2, d2y, a2y), ay);
      ax = fmaf(bf2f(x3.x), fmaf(f3, d3x, a3x), ax);
      ay = fmaf(bf2f(x3.y), fmaf(f3, d3y, a3y), ay);
    }
    for (; j < cnt; ++j){
      int   r0 = __shfl(s_l, j, 64);
      float t0 = __shfl(t_l, j, 64);
      int i00 = (int)t0; if (i00 > 1023) i00 = 1023;
      float f0 = t0 - (float)i00;
      ushort4 p0 = tabl[(size_t)i00*64];
      ushort2 x0 = xh2[(size_t)r0*64];
      float a0x=bf2f(p0.x), a0y=bf2f(p0.y), d0x=bf2f(p0.z)-a0x, d0y=bf2f(p0.w)-a0y;
      ax = fmaf(bf2f(x0.x), fmaf(f0, d0x, a0x), ax);
      ay = fmaf(bf2f(x0.y), fmaf(f0, d0y, a0y), ay);
    }
  }
  ((float2*)(agg + (size_t)c*HDIM))[lane] = make_float2(ax, ay);
}

// ---------------- fused interaction: DMA double-buffered weight chunks ----------------
// Bs dbuf (16K+16K) + Ss 8K = 40 KB -> 4 blocks/CU (same as grid cap).
// One barrier per chunk; next chunk's global_load_lds flies behind the FMA block.
#define FMA_BLOCK(BSP, AROW0, AROW1)                                   \
  _Pragma("unroll")                                                    \
  for (int kk=0; kk<32; kk+=4){                                        \
    float4 b0 = *(const float4*)((BSP) + (kk+0)*HDIM + j0);            \
    float4 b1 = *(const float4*)((BSP) + (kk+1)*HDIM + j0);            \
    float4 b2 = *(const float4*)((BSP) + (kk+2)*HDIM + j0);            \
    float4 b3 = *(const float4*)((BSP) + (kk+3)*HDIM + j0);            \
    float4 a0 = *(const float4*)((AROW0) + kk);                        \
    float4 a1 = *(const float4*)((AROW1) + kk);                        \
    fma4(acc0,a0.x,b0); fma4(acc0,a0.y,b1); fma4(acc0,a0.z,b2); fma4(acc0,a0.w,b3); \
    fma4(acc1,a1.x,b0); fma4(acc1,a1.y,b1); fma4(acc1,a1.z,b2); fma4(acc1,a1.w,b3); \
  }
template<bool LAST>
__global__ __launch_bounds__(256,4) void k_fused3(const float* __restrict__ Ain,
    const float* __restrict__ W2, const float* __restrict__ B2,
    const float* __restrict__ WL, const float* __restrict__ BL,
    float* __restrict__ Hio, const float* __restrict__ W1n, ushort4* __restrict__ Xout){
  __shared__ float BsA[32*HDIM];  // 16 KB
  __shared__ float BsB[32*HDIM];  // 16 KB
  __shared__ float Ss[FR*HDIM];   // 8 KB, holds t then h'
  int tid = threadIdx.x;
  int m0 = blockIdx.x*FR;
  int tc = tid & 31, tr = tid >> 5;
  int j0 = tc*4;
  int lr0 = tr*2, lr1 = tr*2+1;
  float4 acc0, acc1;
  float* Bcur = BsA;
  float* Bnxt = BsB;

  stage_dma(Bcur, W2, 0, tid);
  __syncthreads();                    // DMA chunk0 drained (vmcnt before barrier)

  // ---- stage A: acc = agg @ W2 ----
  acc0 = make_float4(0,0,0,0); acc1 = acc0;
  {
    const float* A0 = Ain + (size_t)(m0 + lr0)*HDIM;
    const float* A1 = Ain + (size_t)(m0 + lr1)*HDIM;
    for (int kc=0; kc<HDIM; kc+=32){
      if (kc+32 < HDIM) stage_dma(Bnxt, W2, kc+32, tid);
      else              stage_dma(Bnxt, WL, 0, tid);        // cross-stage prefetch
      FMA_BLOCK(Bcur, A0 + kc, A1 + kc);
      __syncthreads();
      float* tmp = Bcur; Bcur = Bnxt; Bnxt = tmp;
    }
  }
  {
    float4 b2v = *(const float4*)(B2 + j0);
    float4 v;
    v.x=ssp_f(acc0.x+b2v.x); v.y=ssp_f(acc0.y+b2v.y); v.z=ssp_f(acc0.z+b2v.z); v.w=ssp_f(acc0.w+b2v.w);
    *(float4*)(Ss + lr0*HDIM + j0) = v;
    v.x=ssp_f(acc1.x+b2v.x); v.y=ssp_f(acc1.y+b2v.y); v.z=ssp_f(acc1.z+b2v.z); v.w=ssp_f(acc1.w+b2v.w);
    *(float4*)(Ss + lr1*HDIM + j0) = v;
  }
  __syncthreads();                    // t visible to all before stage B reads

  // ---- stage B: acc = t @ WL ; h' = h + acc + bl ----
  acc0 = make_float4(0,0,0,0); acc1 = acc0;
  for (int kc=0; kc<HDIM; kc+=32){
    if (kc+32 < HDIM)   stage_dma(Bnxt, WL, kc+32, tid);
    else if (!LAST)     stage_dma(Bnxt, W1n, 0, tid);       // cross-stage prefetch
    FMA_BLOCK(Bcur, Ss + lr0*HDIM + kc, Ss + lr1*HDIM + kc);
    __syncthreads();
    float* tmp = Bcur; Bcur = Bnxt; Bnxt = tmp;
  }
  {
    float4 blv = *(const float4*)(BL + j0);
    float* H0 = Hio + (size_t)(m0 + lr0)*HDIM + j0;
    float* H1 = Hio + (size_t)(m0 + lr1)*HDIM + j0;
    float4 hv;
    hv = *(float4*)H0;
    hv.x += acc0.x+blv.x; hv.y += acc0.y+blv.y; hv.z += acc0.z+blv.z; hv.w += acc0.w+blv.w;
    *(float4*)H0 = hv; if (!LAST) *(float4*)(Ss + lr0*HDIM + j0) = hv;
    hv = *(float4*)H1;
    hv.x += acc1.x+blv.x; hv.y += acc1.y+blv.y; hv.z += acc1.z+blv.z; hv.w += acc1.w+blv.w;
    *(float4*)H1 = hv; if (!LAST) *(float4*)(Ss + lr1*HDIM + j0) = hv;
  }
  if (LAST) return;
  __syncthreads();                    // h' visible before stage C reads

  // ---- stage C: xh_next(bf16) = h' @ W1n ----
  acc0 = make_float4(0,0,0,0); acc1 = acc0;
  for (int kc=0; kc<HDIM; kc+=32){
    if (kc+32 < HDIM) stage_dma(Bnxt, W1n, kc+32, tid);
    FMA_BLOCK(Bcur, Ss + lr0*HDIM + kc, Ss + lr1*HDIM + kc);
    __syncthreads();
    float* tmp = Bcur; Bcur = Bnxt; Bnxt = tmp;
  }
  ushort4 o;
  o.x=f2bf(acc0.x); o.y=f2bf(acc0.y); o.z=f2bf(acc0.z); o.w=f2bf(acc0.w);
  Xout[(size_t)(m0 + lr0)*32 + tc] = o;
  o.x=f2bf(acc1.x); o.y=f2bf(acc1.y); o.z=f2bf(acc1.z); o.w=f2bf(acc1.w);
  Xout[(size_t)(m0 + lr1)*32 + tc] = o;
}

// ---------------- output MLP: per-node scalar (no atomics) ----------------
__global__ __launch_bounds__(256) void k_outA(const float* __restrict__ h, const float* __restrict__ w1,
    const float* __restrict__ b1, const float* __restrict__ w2, const float* __restrict__ b2,
    float* __restrict__ nodeval){
  int node = blockIdx.x*4 + (threadIdx.x >> 6);
  int lane = threadIdx.x & 63;
  float acc = b1[lane];
  const float* hrow = h + (size_t)node*HDIM;
  #pragma unroll 4
  for (int k=0;k<HDIM;++k) acc = fmaf(hrow[k], w1[k*64 + lane], acc);
  float s = ssp_f(acc) * w2[lane];
  for (int off=32; off>0; off>>=1) s += __shfl_down(s, off, 64);
  if (lane == 0) nodeval[node] = s + b2[0];
}

// ---------------- graph readout ----------------
__global__ __launch_bounds__(256) void k_outB(const float* __restrict__ nodeval,
    const int* __restrict__ batch, float* __restrict__ out){
  __shared__ float sred[4];
  int g = blockIdx.x;
  int t = threadIdx.x;
  float s = 0.f;
  for (int n = t; n < N_NODES; n += 256)
    if (batch[n] == g) s += nodeval[n];
  for (int off=32; off>0; off>>=1) s += __shfl_down(s, off, 64);
  if ((t & 63) == 0) sred[t >> 6] = s;
  __syncthreads();
  if (t == 0){
    float tot = sred[0] + sred[1] + sred[2] + sred[3];
    out[g] = 1.0f/(1.0f + __expf(-tot));
  }
}

// ---------------- host ----------------
extern "C" void kernel_launch(void* const* d_in, const int* in_sizes, int n_in,
                              void* d_out, int out_size, void* d_ws, size_t ws_size,
                              hipStream_t stream){
  (void)in_sizes; (void)n_in; (void)out_size;
  const int*   z      = (const int*)  d_in[0];
  const float* pos    = (const float*)d_in[1];
  const int*   ei     = (const int*)  d_in[2];
  const int*   batch  = (const int*)  d_in[3];
  const float* emb    = (const float*)d_in[4];
  const float* mlp_w1 = (const float*)d_in[5];
  const float* mlp_b1 = (const float*)d_in[6];
  const float* mlp_w2 = (const float*)d_in[7];
  const float* mlp_b2 = (const float*)d_in[8];
  const float* cf_w1  = (const float*)d_in[9];
  const float* cf_w2  = (const float*)d_in[10];
  const float* cf_b2  = (const float*)d_in[11];
  const float* lin_w  = (const float*)d_in[12];
  const float* lin_b  = (const float*)d_in[13];
  const float* ow1    = (const float*)d_in[14];
  const float* ob1    = (const float*)d_in[15];
  const float* ow2    = (const float*)d_in[16];
  const float* ob2    = (const float*)d_in[17];

  char* wp = (char*)d_ws;
  size_t used = 0;
  auto alloc = [&](size_t bytes)->char*{
    char* p = wp + used;
    used += (bytes + 1023) & ~(size_t)1023;
    return p;
  };
  float*   tab     = (float*)alloc((size_t)NLAYER*TROWS*HDIM*4);
  ushort4* tabp    = (ushort4*)alloc((size_t)NLAYER*1024*64*8);
  float*   h       = (float*)alloc((size_t)N_NODES*HDIM*4);
  ushort4* xhb     = (ushort4*)alloc((size_t)N_NODES*32*8);
  float*   agg     = (float*)alloc((size_t)N_NODES*HDIM*4);
  int*     rowptr  = (int*)  alloc((size_t)(N_NODES+1)*4);
  int*     cursor  = (int*)  alloc((size_t)N_NODES*4);
  int*     srcl    = (int*)  alloc((size_t)N_EDGES*4);
  float*   tl      = (float*)alloc((size_t)N_EDGES*4);
  float*   nodeval = (float*)alloc((size_t)N_NODES*4);
  if (used > ws_size) return;

  hipMemsetAsync(cursor, 0, (size_t)N_NODES*4, stream);

  k_init_h<<<N_NODES*32/256, 256, 0, stream>>>(z, emb, h);
  k_tab   <<<NLAYER*TAB_NB, 256, 0, stream>>>(mlp_w1, mlp_b1, mlp_w2, mlp_b2, tab);
  k_pack  <<<NLAYER*1024*64/256, 256, 0, stream>>>(tab, tabp);
  k_hist  <<<N_EDGES/256, 256, 0, stream>>>(ei, cursor);
  k_scan  <<<1, 1024, 0, stream>>>(cursor, rowptr);
  k_fill  <<<N_EDGES/256, 256, 0, stream>>>(ei, pos, cursor, srcl, tl);

  k_gemm_xh<<<N_NODES/FR, 256, 0, stream>>>(h, cf_w1, xhb);
  for (int l=0; l<NLAYER; ++l){
    k_agg<<<N_NODES/4, 256, 0, stream>>>(rowptr, srcl, tl,
                 tabp + (size_t)l*1024*64, (const ushort2*)xhb, agg);
    if (l < NLAYER-1){
      k_fused3<false><<<N_NODES/FR, 256, 0, stream>>>(agg,
                 cf_w2 + (size_t)l*HDIM*HDIM, cf_b2 + (size_t)l*HDIM,
                 lin_w + (size_t)l*HDIM*HDIM, lin_b + (size_t)l*HDIM, h,
                 cf_w1 + (size_t)(l+1)*HDIM*HDIM, xhb);
    } else {
      k_fused3<true><<<N_NODES/FR, 256, 0, stream>>>(agg,
                 cf_w2 + (size_t)l*HDIM*HDIM, cf_b2 + (size_t)l*HDIM,
                 lin_w + (size_t)l*HDIM*HDIM, lin_b + (size_t)l*HDIM, h,
                 nullptr, nullptr);
    }
  }
  k_outA  <<<N_NODES/4, 256, 0, stream>>>(h, ow1, ob1, ow2, ob2, nodeval);
  k_outB  <<<NGRAPH, 256, 0, stream>>>(nodeval, batch, (float*)d_out);
}